// Round 1
// baseline (804.032 us; speedup 1.0000x reference)
//
#include <hip/hip_runtime.h>
#include <hip/hip_bf16.h>
#include <math.h>

#define IMG 224
#define PIX (IMG*IMG)   // 50176
#define B_ 32
#define E_ 512
#define N_ 4096

typedef __attribute__((ext_vector_type(8))) short bf16x8;
typedef __attribute__((ext_vector_type(4))) float f32x4;

__device__ inline unsigned enc_f(float f){
  unsigned u = __float_as_uint(f);
  return (u & 0x80000000u) ? ~u : (u | 0x80000000u);
}
__device__ inline float dec_f(unsigned u){
  return (u & 0x80000000u) ? __uint_as_float(u & 0x7FFFFFFFu) : __uint_as_float(~u);
}
__device__ inline unsigned short f2bf(float f){
  unsigned u = __float_as_uint(f);
  unsigned r = (u + 0x7FFFu + ((u >> 16) & 1u)) >> 16;  // RNE
  return (unsigned short)r;
}
__device__ inline float wave_sum(float v){
  #pragma unroll
  for (int o = 32; o; o >>= 1) v += __shfl_down(v, o);
  return v;
}

// block = 256 threads (4 waves). Reduces per-thread (mn,mx) candidates and
// atomics encoded results into gmin/gmax.
__device__ inline void block_minmax(float mn, float mx, unsigned* gmin, unsigned* gmax){
  __shared__ float red[16];
  #pragma unroll
  for (int o = 32; o; o >>= 1){
    mn = fminf(mn, __shfl_down(mn, o));
    mx = fmaxf(mx, __shfl_down(mx, o));
  }
  int wv = threadIdx.x >> 6, ln = threadIdx.x & 63;
  __syncthreads();
  if (ln == 0){ red[wv] = mn; red[8 + wv] = mx; }
  __syncthreads();
  if (threadIdx.x == 0){
    float m0 = fminf(fminf(red[0], red[1]), fminf(red[2], red[3]));
    float m1 = fmaxf(fmaxf(red[8], red[9]), fmaxf(red[10], red[11]));
    atomicMin(gmin, enc_f(m0));
    atomicMax(gmax, enc_f(m1));
  }
}

__global__ void init_slots(unsigned* slots){
  int t = threadIdx.x;
  if (t < 6) slots[t] = (t & 1) ? 0u : 0xFFFFFFFFu;  // even=min slot, odd=max slot
}

// one block per (b,e) row: mean over N and 1/(||x-mu||+1e-8)
__global__ void __launch_bounds__(256) row_stats(const float* __restrict__ x,
                                                 float* __restrict__ meanv,
                                                 float* __restrict__ rnormv){
  int row = blockIdx.x;                   // b*512 + e
  const float4* xr = (const float4*)(x + (size_t)row * N_);
  int t = threadIdx.x;
  float s = 0.f, ss = 0.f;
  #pragma unroll
  for (int k = 0; k < 4; k++){
    float4 v = xr[t + 256 * k];
    s  += v.x + v.y + v.z + v.w;
    ss += v.x * v.x + v.y * v.y + v.z * v.z + v.w * v.w;
  }
  __shared__ float red[16];
  float sw = wave_sum(s), ssw = wave_sum(ss);
  int wv = t >> 6, ln = t & 63;
  if (ln == 0){ red[wv] = sw; red[8 + wv] = ssw; }
  __syncthreads();
  if (t == 0){
    float S  = red[0] + red[1] + red[2] + red[3];
    float SS = red[8] + red[9] + red[10] + red[11];
    float mu = S * (1.f / N_);
    float var = fmaxf(SS - S * S * (1.f / N_), 0.f);
    meanv[row]  = mu;
    rnormv[row] = 1.f / (sqrtf(var) + 1e-8f);
  }
}

// colmean[b][n] = mean over E. grid = B*16 blocks of 256 (one thread per n)
__global__ void __launch_bounds__(256) col_mean(const float* __restrict__ x,
                                                float* __restrict__ colmean){
  int b = blockIdx.x >> 4;
  int n = ((blockIdx.x & 15) << 8) + threadIdx.x;
  const float* xp = x + (size_t)b * E_ * N_ + n;
  float s = 0.f;
  #pragma unroll 8
  for (int e = 0; e < E_; e++) s += xp[(size_t)e * N_];
  colmean[b * N_ + n] = s * (1.f / E_);
}

__device__ inline float grid_val(const float* v, int gs, int n, int r, int c){
  int idx = r * gs + c;
  return (idx < n) ? v[idx] : 0.f;
}
// PyTorch-style bilinear (align_corners=False), gs x gs grid -> 224
__device__ inline float bilin(const float* v, int gs, int n, int i, int j){
  float sc = (float)((double)gs / 224.0);
  float r = fmaxf(((float)i + 0.5f) * sc - 0.5f, 0.f);
  float c = fmaxf(((float)j + 0.5f) * sc - 0.5f, 0.f);
  int r0 = min((int)r, gs - 1), c0 = min((int)c, gs - 1);
  int r1 = min(r0 + 1, gs - 1), c1 = min(c0 + 1, gs - 1);
  float wr = r - (float)r0, wc = c - (float)c0;
  float v00 = grid_val(v, gs, n, r0, c0), v10 = grid_val(v, gs, n, r1, c0);
  float v01 = grid_val(v, gs, n, r0, c1), v11 = grid_val(v, gs, n, r1, c1);
  float ra = v00 * (1.f - wr) + v10 * wr;
  float rb = v01 * (1.f - wr) + v11 * wr;
  return ra * (1.f - wc) + rb * wc;
}

// temporal + spatial views, unnormalized, with global minmax accumulation
__global__ void __launch_bounds__(256) small_views(const float* __restrict__ meanv,
                                                   const float* __restrict__ colmean,
                                                   float* __restrict__ out,
                                                   unsigned* slots){
  int b = blockIdx.x / 196;
  int p = (blockIdx.x % 196) * 256 + threadIdx.x;  // < 50176 exactly
  int i = p / IMG, j = p % IMG;
  float tv = bilin(meanv   + b * E_, 23, E_, i, j);
  float sv = bilin(colmean + b * N_, 64, N_, i, j);
  out[((size_t)b * 3 + 0) * PIX + p] = tv;
  out[((size_t)b * 3 + 1) * PIX + p] = sv;
  block_minmax(tv, tv, slots + 0, slots + 1);
  block_minmax(sv, sv, slots + 2, slots + 3);
}

// y[bb][i][:] = a0*x[r0,:] + a1*x[r1,:] + c  (bf16), folding row-normalize + row-resize
__global__ void __launch_bounds__(256) build_y(const float* __restrict__ x,
                                               const float* __restrict__ meanv,
                                               const float* __restrict__ rnormv,
                                               ushort* __restrict__ y, int b0){
  int bb = blockIdx.x / IMG;
  int i  = blockIdx.x % IMG;
  int b  = b0 + bb;
  float sc = (float)(512.0 / 224.0);
  float r = fmaxf(((float)i + 0.5f) * sc - 0.5f, 0.f);
  int r0 = min((int)r, E_ - 1);
  int r1 = min(r0 + 1, E_ - 1);
  float w = r - (float)r0;
  float rn0 = rnormv[b * E_ + r0], rn1 = rnormv[b * E_ + r1];
  float m0  = meanv [b * E_ + r0], m1  = meanv [b * E_ + r1];
  float a0 = (1.f - w) * rn0, a1 = w * rn1;
  float cc = -(a0 * m0 + a1 * m1);
  const float* x0 = x + ((size_t)b * E_ + r0) * N_;
  const float* x1 = x + ((size_t)b * E_ + r1) * N_;
  ushort* yo = y + ((size_t)bb * IMG + i) * N_;
  int c0 = threadIdx.x * 16;
  __align__(16) ushort tmp[16];
  #pragma unroll
  for (int q = 0; q < 4; q++){
    float4 v0 = *(const float4*)(x0 + c0 + q * 4);
    float4 v1 = *(const float4*)(x1 + c0 + q * 4);
    tmp[q * 4 + 0] = f2bf(a0 * v0.x + a1 * v1.x + cc);
    tmp[q * 4 + 1] = f2bf(a0 * v0.y + a1 * v1.y + cc);
    tmp[q * 4 + 2] = f2bf(a0 * v0.z + a1 * v1.z + cc);
    tmp[q * 4 + 3] = f2bf(a0 * v0.w + a1 * v1.w + cc);
  }
  *(int4*)(yo + c0)     = *(int4*)(tmp);
  *(int4*)(yo + c0 + 8) = *(int4*)(tmp + 8);
}

// C_b = y_b * y_b^T (224x224), 64x64 tiles, 4 waves of 2x2 16x16 frags, BK=64
#define LDSTR 72  // padded row stride in bf16 (144 B, 16B-aligned)
__global__ void __launch_bounds__(256) corr_gemm(const ushort* __restrict__ y,
                                                 float* __restrict__ out,
                                                 unsigned* slots, int b0){
  int bb = blockIdx.x >> 4;
  int tile = blockIdx.x & 15;
  int ti = tile >> 2, tj = tile & 3;
  int b = b0 + bb;
  const ushort* yb = y + (size_t)bb * IMG * N_;
  __shared__ ushort lA[64 * LDSTR];
  __shared__ ushort lB[64 * LDSTR];
  int t = threadIdx.x;
  int wv = t >> 6, ln = t & 63;
  int wm = wv & 1, wn = wv >> 1;
  int quad = ln >> 4, l16 = ln & 15;
  f32x4 acc[2][2] = {};
  int s = t & 7, r2 = t >> 3;  // seg (8 bf16 each), row base (0..31)
  int rA0 = min(ti * 64 + r2,      223), rA1 = min(ti * 64 + r2 + 32, 223);
  int rB0 = min(tj * 64 + r2,      223), rB1 = min(tj * 64 + r2 + 32, 223);
  for (int k0 = 0; k0 < N_; k0 += 64){
    int4 a0 = *(const int4*)(yb + (size_t)rA0 * N_ + k0 + s * 8);
    int4 a1 = *(const int4*)(yb + (size_t)rA1 * N_ + k0 + s * 8);
    int4 b0v = *(const int4*)(yb + (size_t)rB0 * N_ + k0 + s * 8);
    int4 b1v = *(const int4*)(yb + (size_t)rB1 * N_ + k0 + s * 8);
    __syncthreads();  // previous iter's compute done
    *(int4*)(lA + r2 * LDSTR + s * 8)        = a0;
    *(int4*)(lA + (r2 + 32) * LDSTR + s * 8) = a1;
    *(int4*)(lB + r2 * LDSTR + s * 8)        = b0v;
    *(int4*)(lB + (r2 + 32) * LDSTR + s * 8) = b1v;
    __syncthreads();
    #pragma unroll
    for (int kk = 0; kk < 2; kk++){
      bf16x8 af0 = *(const bf16x8*)(lA + (wm * 32 + l16)      * LDSTR + kk * 32 + quad * 8);
      bf16x8 af1 = *(const bf16x8*)(lA + (wm * 32 + 16 + l16) * LDSTR + kk * 32 + quad * 8);
      bf16x8 bf0 = *(const bf16x8*)(lB + (wn * 32 + l16)      * LDSTR + kk * 32 + quad * 8);
      bf16x8 bf1 = *(const bf16x8*)(lB + (wn * 32 + 16 + l16) * LDSTR + kk * 32 + quad * 8);
      acc[0][0] = __builtin_amdgcn_mfma_f32_16x16x32_bf16(af0, bf0, acc[0][0], 0, 0, 0);
      acc[0][1] = __builtin_amdgcn_mfma_f32_16x16x32_bf16(af0, bf1, acc[0][1], 0, 0, 0);
      acc[1][0] = __builtin_amdgcn_mfma_f32_16x16x32_bf16(af1, bf0, acc[1][0], 0, 0, 0);
      acc[1][1] = __builtin_amdgcn_mfma_f32_16x16x32_bf16(af1, bf1, acc[1][1], 0, 0, 0);
    }
  }
  float mn = INFINITY, mx = -INFINITY;
  float* ov = out + ((size_t)b * 3 + 2) * PIX;
  #pragma unroll
  for (int im = 0; im < 2; im++)
    #pragma unroll
    for (int in = 0; in < 2; in++){
      #pragma unroll
      for (int rg = 0; rg < 4; rg++){
        int gi = ti * 64 + wm * 32 + im * 16 + quad * 4 + rg;
        int gj = tj * 64 + wn * 32 + in * 16 + l16;
        if (gi < IMG && gj < IMG){
          float v = acc[im][in][rg];
          ov[gi * IMG + gj] = v;
          mn = fminf(mn, v); mx = fmaxf(mx, v);
        }
      }
    }
  block_minmax(mn, mx, slots + 4, slots + 5);
}

__global__ void __launch_bounds__(256) normalize_k(float* __restrict__ out,
                                                   const unsigned* __restrict__ slots){
  int g = blockIdx.x * 256 + threadIdx.x;
  if (g >= B_ * 3 * PIX) return;
  int view = (g / PIX) % 3;  // uniform per block (PIX % 256 == 0)
  float mn = dec_f(slots[2 * view]);
  float mx = dec_f(slots[2 * view + 1]);
  float d = mx - mn;
  float v = out[g];
  out[g] = (d < 1e-8f) ? 0.f : (v - mn) / (d + 1e-8f);
}

extern "C" void kernel_launch(void* const* d_in, const int* in_sizes, int n_in,
                              void* d_out, int out_size, void* d_ws, size_t ws_size,
                              hipStream_t stream){
  const float* x = (const float*)d_in[0];
  float* out = (float*)d_out;
  char* ws = (char*)d_ws;
  // ws layout
  unsigned* slots  = (unsigned*)(ws + 0);            // 6 uints
  float* meanv     = (float*)(ws + 256);             // 16384 f
  float* rnormv    = meanv + B_ * E_;                // 16384 f
  float* colmean   = rnormv + B_ * E_;               // 131072 f
  const size_t Y_OFF = 256 + (size_t)4 * (B_ * E_ * 2 + B_ * N_);  // 655616
  ushort* y = (ushort*)(ws + Y_OFF);
  // pick the largest batch-chunk for y that fits in ws
  int nb = B_;
  while (nb > 1 && Y_OFF + (size_t)nb * IMG * N_ * 2 > ws_size) nb >>= 1;

  hipLaunchKernelGGL(init_slots, dim3(1), dim3(64), 0, stream, slots);
  hipLaunchKernelGGL(row_stats, dim3(B_ * E_), dim3(256), 0, stream, x, meanv, rnormv);
  hipLaunchKernelGGL(col_mean, dim3(B_ * 16), dim3(256), 0, stream, x, colmean);
  hipLaunchKernelGGL(small_views, dim3(B_ * 196), dim3(256), 0, stream,
                     meanv, colmean, out, slots);
  for (int b0 = 0; b0 < B_; b0 += nb){
    hipLaunchKernelGGL(build_y, dim3(nb * IMG), dim3(256), 0, stream,
                       x, meanv, rnormv, y, b0);
    hipLaunchKernelGGL(corr_gemm, dim3(nb * 16), dim3(256), 0, stream,
                       y, out, slots, b0);
  }
  hipLaunchKernelGGL(normalize_k, dim3((B_ * 3 * PIX) / 256), dim3(256), 0, stream,
                     out, slots);
}

// Round 2
// 500.248 us; speedup vs baseline: 1.6073x; 1.6073x over previous
//
#include <hip/hip_runtime.h>
#include <hip/hip_bf16.h>
#include <math.h>

#define IMG 224
#define PIX (IMG*IMG)   // 50176
#define B_ 32
#define E_ 512
#define N_ 4096
#define SV_BLOCKS 256

typedef __attribute__((ext_vector_type(8))) short bf16x8;
typedef __attribute__((ext_vector_type(4))) float f32x4;

__device__ inline unsigned short f2bf(float f){
  unsigned u = __float_as_uint(f);
  unsigned r = (u + 0x7FFFu + ((u >> 16) & 1u)) >> 16;  // RNE
  return (unsigned short)r;
}
__device__ inline float wave_sum(float v){
  #pragma unroll
  for (int o = 32; o; o >>= 1) v += __shfl_down(v, o);
  return v;
}

// ---------------- fused row stats + column partial sums -------------------
// grid = B*16; block handles b = blk>>4, rows e0..e0+31 (e0 = (blk&15)*32).
// Row sums/sumsq -> meanv/rnormv directly. Column partials (16 cols/thread)
// held in registers across the 32 rows, written to colpart[b*16+chunk][4096].
__global__ void __launch_bounds__(256) stats_fused(const float* __restrict__ x,
                                                   float* __restrict__ meanv,
                                                   float* __restrict__ rnormv,
                                                   float* __restrict__ colpart){
  int b = blockIdx.x >> 4, chunk = blockIdx.x & 15;
  int e0 = chunk << 5;
  const float* xb = x + ((size_t)b * E_ + e0) * N_;
  int t = threadIdx.x;
  float csum[16];
  #pragma unroll
  for (int k = 0; k < 16; k++) csum[k] = 0.f;
  __shared__ float red[16];
  float4 v[4];
  const float4* xr0 = (const float4*)xb;
  #pragma unroll
  for (int k = 0; k < 4; k++) v[k] = xr0[t + 256 * k];
  for (int e = 0; e < 32; e++){
    float s = 0.f, ss = 0.f;
    #pragma unroll
    for (int k = 0; k < 4; k++){
      float4 w = v[k];
      csum[4*k+0] += w.x; csum[4*k+1] += w.y;
      csum[4*k+2] += w.z; csum[4*k+3] += w.w;
      s  += w.x + w.y + w.z + w.w;
      ss += w.x*w.x + w.y*w.y + w.z*w.z + w.w*w.w;
    }
    if (e < 31){
      const float4* nx = (const float4*)(xb + (size_t)(e + 1) * N_);
      #pragma unroll
      for (int k = 0; k < 4; k++) v[k] = nx[t + 256 * k];  // prefetch next row
    }
    float sw = wave_sum(s), ssw = wave_sum(ss);
    int wv = t >> 6, ln = t & 63;
    __syncthreads();  // red reuse guard
    if (ln == 0){ red[wv] = sw; red[8 + wv] = ssw; }
    __syncthreads();
    if (t == 0){
      float S  = red[0] + red[1] + red[2] + red[3];
      float SS = red[8] + red[9] + red[10] + red[11];
      float mu = S * (1.f / N_);
      float var = fmaxf(SS - S * S * (1.f / N_), 0.f);
      meanv [b * E_ + e0 + e] = mu;
      rnormv[b * E_ + e0 + e] = 1.f / (sqrtf(var) + 1e-8f);
    }
  }
  float* cp = colpart + ((size_t)(b * 16 + chunk)) * N_;
  #pragma unroll
  for (int k = 0; k < 4; k++){
    float4 o;
    o.x = csum[4*k+0]; o.y = csum[4*k+1]; o.z = csum[4*k+2]; o.w = csum[4*k+3];
    *(float4*)(cp + 1024 * k + 4 * t) = o;
  }
}

// colmean[b][n] = (1/E) * sum over 16 partials
__global__ void __launch_bounds__(256) col_finalize(const float* __restrict__ colpart,
                                                    float* __restrict__ colmean){
  int b = blockIdx.x >> 4;
  int n = ((blockIdx.x & 15) << 8) + threadIdx.x;
  float s = 0.f;
  #pragma unroll
  for (int c = 0; c < 16; c++) s += colpart[((size_t)(b * 16 + c)) * N_ + n];
  colmean[b * N_ + n] = s * (1.f / E_);
}

// ---------------- small views (temporal + spatial) ------------------------
__device__ inline float grid_val(const float* v, int gs, int n, int r, int c){
  int idx = r * gs + c;
  return (idx < n) ? v[idx] : 0.f;
}
__device__ inline float bilin(const float* v, int gs, int n, int i, int j){
  float sc = (float)((double)gs / 224.0);
  float r = fmaxf(((float)i + 0.5f) * sc - 0.5f, 0.f);
  float c = fmaxf(((float)j + 0.5f) * sc - 0.5f, 0.f);
  int r0 = min((int)r, gs - 1), c0 = min((int)c, gs - 1);
  int r1 = min(r0 + 1, gs - 1), c1 = min(c0 + 1, gs - 1);
  float wr = r - (float)r0, wc = c - (float)c0;
  float v00 = grid_val(v, gs, n, r0, c0), v10 = grid_val(v, gs, n, r1, c0);
  float v01 = grid_val(v, gs, n, r0, c1), v11 = grid_val(v, gs, n, r1, c1);
  float ra = v00 * (1.f - wr) + v10 * wr;
  float rb = v01 * (1.f - wr) + v11 * wr;
  return ra * (1.f - wc) + rb * wc;
}

// grid-stride over B*PIX; per-block minmax pairs -> scr[blk*4..+3] (no atomics)
__global__ void __launch_bounds__(256) small_views(const float* __restrict__ meanv,
                                                   const float* __restrict__ colmean,
                                                   float* __restrict__ out,
                                                   float* __restrict__ scr){
  float tmn = INFINITY, tmx = -INFINITY, smn = INFINITY, smx = -INFINITY;
  for (int g = blockIdx.x * 256 + threadIdx.x; g < B_ * PIX; g += SV_BLOCKS * 256){
    int b = g / PIX, p = g - b * PIX;
    int i = p / IMG, j = p - i * IMG;
    float tv = bilin(meanv   + b * E_, 23, E_, i, j);
    float sv = bilin(colmean + b * N_, 64, N_, i, j);
    out[((size_t)b * 3 + 0) * PIX + p] = tv;
    out[((size_t)b * 3 + 1) * PIX + p] = sv;
    tmn = fminf(tmn, tv); tmx = fmaxf(tmx, tv);
    smn = fminf(smn, sv); smx = fmaxf(smx, sv);
  }
  #pragma unroll
  for (int o = 32; o; o >>= 1){
    tmn = fminf(tmn, __shfl_down(tmn, o)); tmx = fmaxf(tmx, __shfl_down(tmx, o));
    smn = fminf(smn, __shfl_down(smn, o)); smx = fmaxf(smx, __shfl_down(smx, o));
  }
  __shared__ float red[4][4];
  int wv = threadIdx.x >> 6, ln = threadIdx.x & 63;
  if (ln == 0){ red[wv][0] = tmn; red[wv][1] = tmx; red[wv][2] = smn; red[wv][3] = smx; }
  __syncthreads();
  if (threadIdx.x == 0){
    scr[blockIdx.x * 4 + 0] = fminf(fminf(red[0][0], red[1][0]), fminf(red[2][0], red[3][0]));
    scr[blockIdx.x * 4 + 1] = fmaxf(fmaxf(red[0][1], red[1][1]), fmaxf(red[2][1], red[3][1]));
    scr[blockIdx.x * 4 + 2] = fminf(fminf(red[0][2], red[1][2]), fminf(red[2][2], red[3][2]));
    scr[blockIdx.x * 4 + 3] = fmaxf(fmaxf(red[0][3], red[1][3]), fmaxf(red[2][3], red[3][3]));
  }
}

// ---------------- correlation path ----------------------------------------
// y[bb][i][:] = a0*x[r0,:] + a1*x[r1,:] + c  (bf16) — fold normalize+row-resize
__global__ void __launch_bounds__(256) build_y(const float* __restrict__ x,
                                               const float* __restrict__ meanv,
                                               const float* __restrict__ rnormv,
                                               ushort* __restrict__ y, int b0){
  int bb = blockIdx.x / IMG;
  int i  = blockIdx.x % IMG;
  int b  = b0 + bb;
  float sc = (float)(512.0 / 224.0);
  float r = fmaxf(((float)i + 0.5f) * sc - 0.5f, 0.f);
  int r0 = min((int)r, E_ - 1);
  int r1 = min(r0 + 1, E_ - 1);
  float w = r - (float)r0;
  float rn0 = rnormv[b * E_ + r0], rn1 = rnormv[b * E_ + r1];
  float m0  = meanv [b * E_ + r0], m1  = meanv [b * E_ + r1];
  float a0 = (1.f - w) * rn0, a1 = w * rn1;
  float cc = -(a0 * m0 + a1 * m1);
  const float* x0 = x + ((size_t)b * E_ + r0) * N_;
  const float* x1 = x + ((size_t)b * E_ + r1) * N_;
  ushort* yo = y + ((size_t)bb * IMG + i) * N_;
  int c0 = threadIdx.x * 16;
  __align__(16) ushort tmp[16];
  #pragma unroll
  for (int q = 0; q < 4; q++){
    float4 v0 = *(const float4*)(x0 + c0 + q * 4);
    float4 v1 = *(const float4*)(x1 + c0 + q * 4);
    tmp[q * 4 + 0] = f2bf(a0 * v0.x + a1 * v1.x + cc);
    tmp[q * 4 + 1] = f2bf(a0 * v0.y + a1 * v1.y + cc);
    tmp[q * 4 + 2] = f2bf(a0 * v0.z + a1 * v1.z + cc);
    tmp[q * 4 + 3] = f2bf(a0 * v0.w + a1 * v1.w + cc);
  }
  *(int4*)(yo + c0)     = *(int4*)(tmp);
  *(int4*)(yo + c0 + 8) = *(int4*)(tmp + 8);
}

// C_b = y_b * y_b^T (224x224), 64x64 tiles, 4 waves of 2x2 16x16 frags, BK=64
#define LDSTR 72  // padded LDS row stride in bf16
__global__ void __launch_bounds__(256) corr_gemm(const ushort* __restrict__ y,
                                                 float* __restrict__ out,
                                                 float* __restrict__ scr, int b0){
  int bb = blockIdx.x >> 4;
  int tile = blockIdx.x & 15;
  int ti = tile >> 2, tj = tile & 3;
  int b = b0 + bb;
  const ushort* yb = y + (size_t)bb * IMG * N_;
  __shared__ ushort lA[64 * LDSTR];
  __shared__ ushort lB[64 * LDSTR];
  int t = threadIdx.x;
  int wv = t >> 6, ln = t & 63;
  int wm = wv & 1, wn = wv >> 1;
  int quad = ln >> 4, l16 = ln & 15;
  f32x4 acc[2][2] = {};
  int s = t & 7, r2 = t >> 3;
  int rA0 = min(ti * 64 + r2,      223), rA1 = min(ti * 64 + r2 + 32, 223);
  int rB0 = min(tj * 64 + r2,      223), rB1 = min(tj * 64 + r2 + 32, 223);
  for (int k0 = 0; k0 < N_; k0 += 64){
    int4 a0 = *(const int4*)(yb + (size_t)rA0 * N_ + k0 + s * 8);
    int4 a1 = *(const int4*)(yb + (size_t)rA1 * N_ + k0 + s * 8);
    int4 b0v = *(const int4*)(yb + (size_t)rB0 * N_ + k0 + s * 8);
    int4 b1v = *(const int4*)(yb + (size_t)rB1 * N_ + k0 + s * 8);
    __syncthreads();
    *(int4*)(lA + r2 * LDSTR + s * 8)        = a0;
    *(int4*)(lA + (r2 + 32) * LDSTR + s * 8) = a1;
    *(int4*)(lB + r2 * LDSTR + s * 8)        = b0v;
    *(int4*)(lB + (r2 + 32) * LDSTR + s * 8) = b1v;
    __syncthreads();
    #pragma unroll
    for (int kk = 0; kk < 2; kk++){
      bf16x8 af0 = *(const bf16x8*)(lA + (wm * 32 + l16)      * LDSTR + kk * 32 + quad * 8);
      bf16x8 af1 = *(const bf16x8*)(lA + (wm * 32 + 16 + l16) * LDSTR + kk * 32 + quad * 8);
      bf16x8 bf0 = *(const bf16x8*)(lB + (wn * 32 + l16)      * LDSTR + kk * 32 + quad * 8);
      bf16x8 bf1 = *(const bf16x8*)(lB + (wn * 32 + 16 + l16) * LDSTR + kk * 32 + quad * 8);
      acc[0][0] = __builtin_amdgcn_mfma_f32_16x16x32_bf16(af0, bf0, acc[0][0], 0, 0, 0);
      acc[0][1] = __builtin_amdgcn_mfma_f32_16x16x32_bf16(af0, bf1, acc[0][1], 0, 0, 0);
      acc[1][0] = __builtin_amdgcn_mfma_f32_16x16x32_bf16(af1, bf0, acc[1][0], 0, 0, 0);
      acc[1][1] = __builtin_amdgcn_mfma_f32_16x16x32_bf16(af1, bf1, acc[1][1], 0, 0, 0);
    }
  }
  float mn = INFINITY, mx = -INFINITY;
  float* ov = out + ((size_t)b * 3 + 2) * PIX;
  #pragma unroll
  for (int im = 0; im < 2; im++)
    #pragma unroll
    for (int in = 0; in < 2; in++){
      #pragma unroll
      for (int rg = 0; rg < 4; rg++){
        int gi = ti * 64 + wm * 32 + im * 16 + quad * 4 + rg;
        int gj = tj * 64 + wn * 32 + in * 16 + l16;
        if (gi < IMG && gj < IMG){
          float v = acc[im][in][rg];
          ov[gi * IMG + gj] = v;
          mn = fminf(mn, v); mx = fmaxf(mx, v);
        }
      }
    }
  #pragma unroll
  for (int o = 32; o; o >>= 1){
    mn = fminf(mn, __shfl_down(mn, o)); mx = fmaxf(mx, __shfl_down(mx, o));
  }
  __shared__ float red[4][2];
  if (ln == 0){ red[wv][0] = mn; red[wv][1] = mx; }
  __syncthreads();
  if (t == 0){
    scr[(b * 16 + tile) * 2 + 0] = fminf(fminf(red[0][0], red[1][0]), fminf(red[2][0], red[3][0]));
    scr[(b * 16 + tile) * 2 + 1] = fmaxf(fmaxf(red[0][1], red[1][1]), fmaxf(red[2][1], red[3][1]));
  }
}

// ---------------- final minmax reduce + normalize --------------------------
__global__ void __launch_bounds__(256) reduce_slots(const float* __restrict__ sv_scr,
                                                    const float* __restrict__ corr_scr,
                                                    float* __restrict__ slots){
  int t = threadIdx.x;
  float tmn = sv_scr[4*t+0], tmx = sv_scr[4*t+1];
  float smn = sv_scr[4*t+2], smx = sv_scr[4*t+3];
  float cmn = fminf(corr_scr[2*t],   corr_scr[2*(t+256)]);
  float cmx = fmaxf(corr_scr[2*t+1], corr_scr[2*(t+256)+1]);
  #pragma unroll
  for (int o = 32; o; o >>= 1){
    tmn = fminf(tmn, __shfl_down(tmn, o)); tmx = fmaxf(tmx, __shfl_down(tmx, o));
    smn = fminf(smn, __shfl_down(smn, o)); smx = fmaxf(smx, __shfl_down(smx, o));
    cmn = fminf(cmn, __shfl_down(cmn, o)); cmx = fmaxf(cmx, __shfl_down(cmx, o));
  }
  __shared__ float red[4][6];
  int wv = t >> 6, ln = t & 63;
  if (ln == 0){
    red[wv][0]=tmn; red[wv][1]=tmx; red[wv][2]=smn;
    red[wv][3]=smx; red[wv][4]=cmn; red[wv][5]=cmx;
  }
  __syncthreads();
  if (t == 0){
    slots[0] = fminf(fminf(red[0][0],red[1][0]), fminf(red[2][0],red[3][0]));
    slots[1] = fmaxf(fmaxf(red[0][1],red[1][1]), fmaxf(red[2][1],red[3][1]));
    slots[2] = fminf(fminf(red[0][2],red[1][2]), fminf(red[2][2],red[3][2]));
    slots[3] = fmaxf(fmaxf(red[0][3],red[1][3]), fmaxf(red[2][3],red[3][3]));
    slots[4] = fminf(fminf(red[0][4],red[1][4]), fminf(red[2][4],red[3][4]));
    slots[5] = fmaxf(fmaxf(red[0][5],red[1][5]), fmaxf(red[2][5],red[3][5]));
  }
}

__global__ void __launch_bounds__(256) normalize_k(float* __restrict__ out,
                                                   const float* __restrict__ slots){
  int g = blockIdx.x * 256 + threadIdx.x;
  if (g >= B_ * 3 * PIX) return;
  int view = (g / PIX) % 3;  // uniform per block (PIX % 256 == 0)
  float mn = slots[2 * view];
  float mx = slots[2 * view + 1];
  float d = mx - mn;
  float v = out[g];
  out[g] = (d < 1e-8f) ? 0.f : (v - mn) / (d + 1e-8f);
}

extern "C" void kernel_launch(void* const* d_in, const int* in_sizes, int n_in,
                              void* d_out, int out_size, void* d_ws, size_t ws_size,
                              hipStream_t stream){
  const float* x = (const float*)d_in[0];
  float* out = (float*)d_out;
  char* ws = (char*)d_ws;
  float* slots    = (float*)(ws + 0);                   // 6 f (slot pad 256 B)
  float* meanv    = (float*)(ws + 256);                 // 16384 f
  float* rnormv   = meanv + B_ * E_;                    // 16384 f
  float* colmean  = rnormv + B_ * E_;                   // 131072 f
  float* colpart  = colmean + B_ * N_;                  // 32*16*4096 f (8 MB)
  float* sv_scr   = colpart + (size_t)B_ * 16 * N_;     // SV_BLOCKS*4 f
  float* corr_scr = sv_scr + SV_BLOCKS * 4;             // 1024 f
  size_t y_off = ((size_t)((char*)(corr_scr + B_ * 16 * 2) - ws) + 255) & ~(size_t)255;
  ushort* y = (ushort*)(ws + y_off);
  int nb = B_;
  while (nb > 1 && y_off + (size_t)nb * IMG * N_ * 2 > ws_size) nb >>= 1;

  hipLaunchKernelGGL(stats_fused, dim3(B_ * 16), dim3(256), 0, stream,
                     x, meanv, rnormv, colpart);
  hipLaunchKernelGGL(col_finalize, dim3(B_ * 16), dim3(256), 0, stream,
                     colpart, colmean);
  hipLaunchKernelGGL(small_views, dim3(SV_BLOCKS), dim3(256), 0, stream,
                     meanv, colmean, out, sv_scr);
  for (int b0 = 0; b0 < B_; b0 += nb){
    hipLaunchKernelGGL(build_y, dim3(nb * IMG), dim3(256), 0, stream,
                       x, meanv, rnormv, y, b0);
    hipLaunchKernelGGL(corr_gemm, dim3(nb * 16), dim3(256), 0, stream,
                       y, out, corr_scr, b0);
  }
  hipLaunchKernelGGL(reduce_slots, dim3(1), dim3(256), 0, stream,
                     sv_scr, corr_scr, slots);
  hipLaunchKernelGGL(normalize_k, dim3((B_ * 3 * PIX + 255) / 256), dim3(256), 0, stream,
                     out, slots);
}

// Round 3
// 460.123 us; speedup vs baseline: 1.7474x; 1.0872x over previous
//
#include <hip/hip_runtime.h>
#include <hip/hip_bf16.h>
#include <math.h>

#define IMG 224
#define PIX (IMG*IMG)   // 50176
#define B_ 32
#define E_ 512
#define N_ 4096
#define SV_BLOCKS 256
#define SC_ ((float)(512.0/224.0))

typedef __attribute__((ext_vector_type(8))) short bf16x8;
typedef __attribute__((ext_vector_type(4))) float f32x4;

__device__ inline unsigned short f2bf(float f){
  unsigned u = __float_as_uint(f);
  unsigned r = (u + 0x7FFFu + ((u >> 16) & 1u)) >> 16;  // RNE
  return (unsigned short)r;
}

// ---------- fused: row stats + column partials + inline y emission ----------
// grid = B*16. Block: batch b, source rows e0..e0+31 (reads e0..e0+32).
// y row i (= resized+normalized row) emitted when both source rows of its
// 2-tap stencil have stats ready; r0(i) in [e0, e0+31] owned by this block.
__global__ void __launch_bounds__(256) stats_y(const float* __restrict__ x,
                                               float* __restrict__ meanv,
                                               float* __restrict__ colpart,
                                               ushort* __restrict__ y){
  int b = blockIdx.x >> 4, chunk = blockIdx.x & 15;
  int e0 = chunk << 5;
  int t = threadIdx.x;
  __shared__ short sInv[512];   // src row r0 -> output row i (or -1)
  __shared__ float sW[224];     // interp weight per output row
  __shared__ float red[2][16];  // parity-buffered block reduction slab
  sInv[t] = -1; sInv[t + 256] = -1;
  __syncthreads();
  if (t < 224){
    float r = fmaxf(((float)t + 0.5f) * SC_ - 0.5f, 0.f);
    int r0 = min((int)r, E_ - 1);
    sW[t] = r - (float)r0;
    sInv[r0] = (short)t;        // scale > 2 => at most one i per r0, no race
  }
  __syncthreads();

  float cur[16], prev[16], nxt[16], csum[16];
  #pragma unroll
  for (int j = 0; j < 16; j++){ csum[j] = 0.f; prev[j] = 0.f; }
  const float4* row0 = (const float4*)(x + ((size_t)b * E_ + e0) * N_);
  #pragma unroll
  for (int k = 0; k < 4; k++) *(float4*)(cur + 4 * k) = row0[4 * t + k];
  float pmu = 0.f, prn = 0.f;

  for (int idx = 0; idx <= 32; idx++){
    int e = e0 + idx;
    if (e >= E_) break;
    bool hasNext = (idx < 32) && (e + 1 < E_);
    if (hasNext){
      const float4* nr = (const float4*)(x + ((size_t)b * E_ + e + 1) * N_);
      #pragma unroll
      for (int k = 0; k < 4; k++) *(float4*)(nxt + 4 * k) = nr[4 * t + k];
    }
    float s = 0.f, ss = 0.f;
    #pragma unroll
    for (int j = 0; j < 16; j++){ s += cur[j]; ss += cur[j] * cur[j]; }
    #pragma unroll
    for (int o = 32; o; o >>= 1){ s += __shfl_down(s, o); ss += __shfl_down(ss, o); }
    int wv = t >> 6, ln = t & 63, p = idx & 1;
    if (ln == 0){ red[p][wv] = s; red[p][8 + wv] = ss; }
    __syncthreads();    // single barrier per row (parity buffer handles reuse)
    float S  = red[p][0] + red[p][1] + red[p][2] + red[p][3];
    float SS = red[p][8] + red[p][9] + red[p][10] + red[p][11];
    float mu = S * (1.f / N_);
    float var = fmaxf(SS - S * S * (1.f / N_), 0.f);
    float rn = 1.f / (sqrtf(var) + 1e-8f);
    if (idx < 32){
      #pragma unroll
      for (int j = 0; j < 16; j++) csum[j] += cur[j];
      if (t == 0) meanv[b * E_ + e] = mu;
    }
    if (idx >= 1){
      int i = sInv[e - 1];
      if (i >= 0){
        float w = sW[i];
        float a0 = (1.f - w) * prn, a1 = w * rn;
        float cc = -(a0 * pmu + a1 * mu);
        __align__(16) ushort tmp[16];
        #pragma unroll
        for (int j = 0; j < 16; j++) tmp[j] = f2bf(a0 * prev[j] + a1 * cur[j] + cc);
        ushort* yo = y + ((size_t)b * IMG + i) * N_ + t * 16;
        *(int4*)yo       = *(int4*)tmp;
        *(int4*)(yo + 8) = *(int4*)(tmp + 8);
      }
    }
    pmu = mu; prn = rn;
    #pragma unroll
    for (int j = 0; j < 16; j++){ prev[j] = cur[j]; if (hasNext) cur[j] = nxt[j]; }
  }
  float* cp = colpart + ((size_t)(b * 16 + chunk)) * N_ + t * 16;
  #pragma unroll
  for (int k = 0; k < 4; k++) *(float4*)(cp + 4 * k) = *(float4*)(csum + 4 * k);
}

// colmean[b][n] = (1/E) * sum of 16 partials
__global__ void __launch_bounds__(256) col_finalize(const float* __restrict__ colpart,
                                                    float* __restrict__ colmean){
  int b = blockIdx.x >> 4;
  int n = ((blockIdx.x & 15) << 8) + threadIdx.x;
  float s = 0.f;
  #pragma unroll
  for (int c = 0; c < 16; c++) s += colpart[((size_t)(b * 16 + c)) * N_ + n];
  colmean[b * N_ + n] = s * (1.f / E_);
}

// ---------------- small views (temporal + spatial) ------------------------
__device__ inline float grid_val(const float* v, int gs, int n, int r, int c){
  int idx = r * gs + c;
  return (idx < n) ? v[idx] : 0.f;
}
__device__ inline float bilin(const float* v, int gs, int n, int i, int j){
  float sc = (float)((double)gs / 224.0);
  float r = fmaxf(((float)i + 0.5f) * sc - 0.5f, 0.f);
  float c = fmaxf(((float)j + 0.5f) * sc - 0.5f, 0.f);
  int r0 = min((int)r, gs - 1), c0 = min((int)c, gs - 1);
  int r1 = min(r0 + 1, gs - 1), c1 = min(c0 + 1, gs - 1);
  float wr = r - (float)r0, wc = c - (float)c0;
  float v00 = grid_val(v, gs, n, r0, c0), v10 = grid_val(v, gs, n, r1, c0);
  float v01 = grid_val(v, gs, n, r0, c1), v11 = grid_val(v, gs, n, r1, c1);
  float ra = v00 * (1.f - wr) + v10 * wr;
  float rb = v01 * (1.f - wr) + v11 * wr;
  return ra * (1.f - wc) + rb * wc;
}

__global__ void __launch_bounds__(256) small_views(const float* __restrict__ meanv,
                                                   const float* __restrict__ colmean,
                                                   float* __restrict__ out,
                                                   float* __restrict__ scr){
  float tmn = INFINITY, tmx = -INFINITY, smn = INFINITY, smx = -INFINITY;
  for (int g = blockIdx.x * 256 + threadIdx.x; g < B_ * PIX; g += SV_BLOCKS * 256){
    int b = g / PIX, p = g - b * PIX;
    int i = p / IMG, j = p - i * IMG;
    float tv = bilin(meanv   + b * E_, 23, E_, i, j);
    float sv = bilin(colmean + b * N_, 64, N_, i, j);
    out[((size_t)b * 3 + 0) * PIX + p] = tv;
    out[((size_t)b * 3 + 1) * PIX + p] = sv;
    tmn = fminf(tmn, tv); tmx = fmaxf(tmx, tv);
    smn = fminf(smn, sv); smx = fmaxf(smx, sv);
  }
  #pragma unroll
  for (int o = 32; o; o >>= 1){
    tmn = fminf(tmn, __shfl_down(tmn, o)); tmx = fmaxf(tmx, __shfl_down(tmx, o));
    smn = fminf(smn, __shfl_down(smn, o)); smx = fmaxf(smx, __shfl_down(smx, o));
  }
  __shared__ float red[4][4];
  int wv = threadIdx.x >> 6, ln = threadIdx.x & 63;
  if (ln == 0){ red[wv][0] = tmn; red[wv][1] = tmx; red[wv][2] = smn; red[wv][3] = smx; }
  __syncthreads();
  if (threadIdx.x == 0){
    scr[blockIdx.x * 4 + 0] = fminf(fminf(red[0][0], red[1][0]), fminf(red[2][0], red[3][0]));
    scr[blockIdx.x * 4 + 1] = fmaxf(fmaxf(red[0][1], red[1][1]), fmaxf(red[2][1], red[3][1]));
    scr[blockIdx.x * 4 + 2] = fminf(fminf(red[0][2], red[1][2]), fminf(red[2][2], red[3][2]));
    scr[blockIdx.x * 4 + 3] = fmaxf(fmaxf(red[0][3], red[1][3]), fmaxf(red[2][3], red[3][3]));
  }
}

// ---------------- correlation GEMM: C = y*y^T, symmetric tiles only --------
#define LDSTR 72
__global__ void __launch_bounds__(256) corr_gemm(const ushort* __restrict__ y,
                                                 float* __restrict__ out,
                                                 float* __restrict__ scr){
  const int TI[10] = {0,0,0,0,1,1,1,2,2,3};
  const int TJ[10] = {0,1,2,3,1,2,3,2,3,3};
  int b = blockIdx.x / 10;
  int tile = blockIdx.x - b * 10;
  int ti = TI[tile], tj = TJ[tile];
  bool diag = (ti == tj);
  const ushort* yb = y + (size_t)b * IMG * N_;
  __shared__ ushort lA[64 * LDSTR];
  __shared__ ushort lB[64 * LDSTR];
  int t = threadIdx.x;
  int wv = t >> 6, ln = t & 63;
  int wm = wv & 1, wn = wv >> 1;
  int quad = ln >> 4, l16 = ln & 15;
  f32x4 acc[2][2] = {};
  int s = t & 7, r2 = t >> 3;
  int rA0 = min(ti * 64 + r2,      223), rA1 = min(ti * 64 + r2 + 32, 223);
  int rB0 = min(tj * 64 + r2,      223), rB1 = min(tj * 64 + r2 + 32, 223);
  for (int k0 = 0; k0 < N_; k0 += 64){
    int4 a0 = *(const int4*)(yb + (size_t)rA0 * N_ + k0 + s * 8);
    int4 a1 = *(const int4*)(yb + (size_t)rA1 * N_ + k0 + s * 8);
    int4 b0v = *(const int4*)(yb + (size_t)rB0 * N_ + k0 + s * 8);
    int4 b1v = *(const int4*)(yb + (size_t)rB1 * N_ + k0 + s * 8);
    __syncthreads();
    *(int4*)(lA + r2 * LDSTR + s * 8)        = a0;
    *(int4*)(lA + (r2 + 32) * LDSTR + s * 8) = a1;
    *(int4*)(lB + r2 * LDSTR + s * 8)        = b0v;
    *(int4*)(lB + (r2 + 32) * LDSTR + s * 8) = b1v;
    __syncthreads();
    #pragma unroll
    for (int kk = 0; kk < 2; kk++){
      bf16x8 af0 = *(const bf16x8*)(lA + (wm * 32 + l16)      * LDSTR + kk * 32 + quad * 8);
      bf16x8 af1 = *(const bf16x8*)(lA + (wm * 32 + 16 + l16) * LDSTR + kk * 32 + quad * 8);
      bf16x8 bf0 = *(const bf16x8*)(lB + (wn * 32 + l16)      * LDSTR + kk * 32 + quad * 8);
      bf16x8 bf1 = *(const bf16x8*)(lB + (wn * 32 + 16 + l16) * LDSTR + kk * 32 + quad * 8);
      acc[0][0] = __builtin_amdgcn_mfma_f32_16x16x32_bf16(af0, bf0, acc[0][0], 0, 0, 0);
      acc[0][1] = __builtin_amdgcn_mfma_f32_16x16x32_bf16(af0, bf1, acc[0][1], 0, 0, 0);
      acc[1][0] = __builtin_amdgcn_mfma_f32_16x16x32_bf16(af1, bf0, acc[1][0], 0, 0, 0);
      acc[1][1] = __builtin_amdgcn_mfma_f32_16x16x32_bf16(af1, bf1, acc[1][1], 0, 0, 0);
    }
  }
  float mn = INFINITY, mx = -INFINITY;
  float* ov = out + ((size_t)b * 3 + 2) * PIX;
  #pragma unroll
  for (int im = 0; im < 2; im++)
    #pragma unroll
    for (int in = 0; in < 2; in++){
      int gi0 = ti * 64 + wm * 32 + im * 16 + quad * 4;
      int gj  = tj * 64 + wn * 32 + in * 16 + l16;
      #pragma unroll
      for (int rg = 0; rg < 4; rg++){
        int gi = gi0 + rg;
        if (gi < IMG && gj < IMG){
          float v = acc[im][in][rg];
          ov[gi * IMG + gj] = v;
          mn = fminf(mn, v); mx = fmaxf(mx, v);
        }
      }
      if (!diag && gj < IMG && gi0 < IMG){   // mirrored tile, packed store
        float4 tv;
        tv.x = acc[im][in][0]; tv.y = acc[im][in][1];
        tv.z = acc[im][in][2]; tv.w = acc[im][in][3];
        *(float4*)(ov + gj * IMG + gi0) = tv;
      }
    }
  #pragma unroll
  for (int o = 32; o; o >>= 1){
    mn = fminf(mn, __shfl_down(mn, o)); mx = fmaxf(mx, __shfl_down(mx, o));
  }
  __shared__ float red[4][2];
  if (ln == 0){ red[wv][0] = mn; red[wv][1] = mx; }
  __syncthreads();
  if (t == 0){
    scr[(b * 10 + tile) * 2 + 0] = fminf(fminf(red[0][0], red[1][0]), fminf(red[2][0], red[3][0]));
    scr[(b * 10 + tile) * 2 + 1] = fmaxf(fmaxf(red[0][1], red[1][1]), fmaxf(red[2][1], red[3][1]));
  }
}

// ---------------- final minmax reduce + normalize --------------------------
__global__ void __launch_bounds__(256) reduce_slots(const float* __restrict__ sv_scr,
                                                    const float* __restrict__ corr_scr,
                                                    float* __restrict__ slots){
  int t = threadIdx.x;
  float tmn = sv_scr[4*t+0], tmx = sv_scr[4*t+1];
  float smn = sv_scr[4*t+2], smx = sv_scr[4*t+3];
  float cmn = INFINITY, cmx = -INFINITY;
  for (int idx = t; idx < B_ * 10; idx += 256){
    cmn = fminf(cmn, corr_scr[2*idx]);
    cmx = fmaxf(cmx, corr_scr[2*idx+1]);
  }
  #pragma unroll
  for (int o = 32; o; o >>= 1){
    tmn = fminf(tmn, __shfl_down(tmn, o)); tmx = fmaxf(tmx, __shfl_down(tmx, o));
    smn = fminf(smn, __shfl_down(smn, o)); smx = fmaxf(smx, __shfl_down(smx, o));
    cmn = fminf(cmn, __shfl_down(cmn, o)); cmx = fmaxf(cmx, __shfl_down(cmx, o));
  }
  __shared__ float red[4][6];
  int wv = t >> 6, ln = t & 63;
  if (ln == 0){
    red[wv][0]=tmn; red[wv][1]=tmx; red[wv][2]=smn;
    red[wv][3]=smx; red[wv][4]=cmn; red[wv][5]=cmx;
  }
  __syncthreads();
  if (t == 0){
    slots[0] = fminf(fminf(red[0][0],red[1][0]), fminf(red[2][0],red[3][0]));
    slots[1] = fmaxf(fmaxf(red[0][1],red[1][1]), fmaxf(red[2][1],red[3][1]));
    slots[2] = fminf(fminf(red[0][2],red[1][2]), fminf(red[2][2],red[3][2]));
    slots[3] = fmaxf(fmaxf(red[0][3],red[1][3]), fmaxf(red[2][3],red[3][3]));
    slots[4] = fminf(fminf(red[0][4],red[1][4]), fminf(red[2][4],red[3][4]));
    slots[5] = fmaxf(fmaxf(red[0][5],red[1][5]), fmaxf(red[2][5],red[3][5]));
  }
}

__global__ void __launch_bounds__(256) normalize_k(float* __restrict__ out,
                                                   const float* __restrict__ slots){
  int g = blockIdx.x * 256 + threadIdx.x;
  if (g >= B_ * 3 * PIX) return;
  int view = (g / PIX) % 3;  // uniform per block (PIX % 256 == 0)
  float mn = slots[2 * view];
  float mx = slots[2 * view + 1];
  float d = mx - mn;
  float v = out[g];
  out[g] = (d < 1e-8f) ? 0.f : (v - mn) / (d + 1e-8f);
}

extern "C" void kernel_launch(void* const* d_in, const int* in_sizes, int n_in,
                              void* d_out, int out_size, void* d_ws, size_t ws_size,
                              hipStream_t stream){
  const float* x = (const float*)d_in[0];
  float* out = (float*)d_out;
  char* ws = (char*)d_ws;
  float* slots    = (float*)(ws + 0);                   // 6 f (pad 256 B)
  float* meanv    = (float*)(ws + 256);                 // B*E f
  float* colmean  = meanv + B_ * E_;                    // B*N f
  float* colpart  = colmean + B_ * N_;                  // B*16*N f (8 MB)
  float* sv_scr   = colpart + (size_t)B_ * 16 * N_;     // SV_BLOCKS*4 f
  float* corr_scr = sv_scr + SV_BLOCKS * 4;             // 640 f
  size_t y_off = ((size_t)((char*)(corr_scr + B_ * 10 * 2) - ws) + 255) & ~(size_t)255;
  ushort* y = (ushort*)(ws + y_off);                    // B*224*4096 bf16 (58.7 MB)

  hipLaunchKernelGGL(stats_y, dim3(B_ * 16), dim3(256), 0, stream,
                     x, meanv, colpart, y);
  hipLaunchKernelGGL(col_finalize, dim3(B_ * 16), dim3(256), 0, stream,
                     colpart, colmean);
  hipLaunchKernelGGL(small_views, dim3(SV_BLOCKS), dim3(256), 0, stream,
                     meanv, colmean, out, sv_scr);
  hipLaunchKernelGGL(corr_gemm, dim3(B_ * 10), dim3(256), 0, stream,
                     y, out, corr_scr);
  hipLaunchKernelGGL(reduce_slots, dim3(1), dim3(256), 0, stream,
                     sv_scr, corr_scr, slots);
  hipLaunchKernelGGL(normalize_k, dim3((B_ * 3 * PIX + 255) / 256), dim3(256), 0, stream,
                     out, slots);
}